// Round 6
// baseline (396.204 us; speedup 1.0000x reference)
//
#include <hip/hip_runtime.h>
#include <cstdint>
#include <cstddef>

typedef float v4f __attribute__((ext_vector_type(4)));
typedef short v8s __attribute__((ext_vector_type(8)));
typedef unsigned short v4u __attribute__((ext_vector_type(4)));

typedef unsigned short ubf;   // raw bf16 bits

#define NPTS 16384
#define CD   256
#define NBAT 4
#define NPB  4096

__device__ __forceinline__ float bf2f(ubf u) {
    union { unsigned u; float f; } c; c.u = ((unsigned)u) << 16; return c.f;
}
__device__ __forceinline__ ubf f2bf(float f) {
    union { float f; unsigned u; } c; c.f = f;
    unsigned u = c.u;
    u += 0x7fffu + ((u >> 16) & 1u);           // round-nearest-even
    return (ubf)(u >> 16);
}
__device__ __forceinline__ ubf f2bf_trunc(float f) {
    union { float f; unsigned u; } c; c.f = f;
    return (ubf)(c.u >> 16);                   // truncate (P-values only)
}

// -------- weight transpose+convert: W[K][256] f32 -> WT[256][K] bf16 ---------
__global__ void k_wtrans(const float* __restrict__ bott, const float* __restrict__ qkv,
                         const float* __restrict__ mlp, const float* __restrict__ fus,
                         ubf* __restrict__ wt) {
    const int z = blockIdx.z;
    const float* src; int K; size_t doff;
    if (z < 6)       { src = bott + (size_t)z * 65536;       K = 256; doff = (size_t)z * 65536; }
    else if (z < 9)  { src = qkv  + (size_t)(z - 6) * 65536; K = 256; doff = (size_t)z * 65536; }
    else if (z < 11) { src = mlp  + (size_t)(z - 9) * 65536; K = 256; doff = (size_t)z * 65536; }
    else             { src = fus;                            K = 512; doff = (size_t)11 * 65536; }
    const int kt = blockIdx.y * 32, nt = blockIdx.x * 32;
    if (kt >= K) return;
    __shared__ ubf tile[32][33];
    const int tx = threadIdx.x, ty = threadIdx.y;   // block (32,8)
#pragma unroll
    for (int i = 0; i < 4; ++i)
        tile[ty * 4 + i][tx] = f2bf(src[(size_t)(kt + ty * 4 + i) * 256 + nt + tx]);
    __syncthreads();
    ubf* dst = wt + doff;
#pragma unroll
    for (int i = 0; i < 4; ++i)
        dst[(size_t)(nt + ty * 4 + i) * K + kt + tx] = tile[tx][ty * 4 + i];
}

// ---------------- point attention (reference's Point_Attentation) ------------
__global__ __launch_bounds__(256) void k_point_attn(const float* __restrict__ low,
                                                    float* __restrict__ xout) {
    const int lane = threadIdx.x & 63;
    const int row  = blockIdx.x * 4 + (threadIdx.x >> 6);
    const float* p = low + (size_t)row * CD + lane * 4;
    v4f v = *reinterpret_cast<const v4f*>(p);
    float d[4];
    float s = v[0] + v[1] + v[2] + v[3];
#pragma unroll
    for (int o = 32; o >= 1; o >>= 1) s += __shfl_xor(s, o);
    const float mean = s * (1.0f / 256.0f);
    float ss = 0.f;
#pragma unroll
    for (int i = 0; i < 4; ++i) { d[i] = v[i] - mean; ss += d[i] * d[i]; }
#pragma unroll
    for (int o = 32; o >= 1; o >>= 1) ss += __shfl_xor(ss, o);
    const float var = ss * (1.0f / 4095.0f);        // reference: /(n-1), n=4096
    const float dn  = 1.0f / (4.0f * (var + 1e-5f));
    v4f o;
#pragma unroll
    for (int i = 0; i < 4; ++i) {
        const float e   = d[i] * d[i] * dn + 0.5f;
        const float sig = 1.0f / (1.0f + __expf(-e));
        o[i] = v[i] * (1.0f + sig);
    }
    *reinterpret_cast<v4f*>(xout + (size_t)row * CD + lane * 4) = o;
}

// ---------------- fused GEMM + bias + BN + ReLU + residual -------------------
// C[M][256] = A[M][K] @ W[K][256], W given as WT[256][K] bf16.
// Block tile 128x128, 4 waves (2x2), wave tile 64x64. grid (M/128, N/128).
// ASRC: 0 = bf16 A (stride K), 1 = f32 A (stride 256), 2 = cat(f32 x | bf16 h)
// OUT:  0 = bf16 [row][col], 1 = f32 [row][col], 2 = bf16 transposed VT[b][col][key]
template<int ASRC, bool BIAS, bool RELU, bool RES, int OUT>
__global__ __launch_bounds__(256) void k_gemm(
    const ubf* __restrict__ Abf, const float* __restrict__ Af, const ubf* __restrict__ A2,
    const ubf* __restrict__ WT, const int K,
    const float* __restrict__ bias, const float* __restrict__ gamma, const float* __restrict__ beta,
    const float* __restrict__ bmean, const float* __restrict__ bvar,
    const float* __restrict__ resid, float* __restrict__ outf, ubf* __restrict__ outb) {
    const int lane = threadIdx.x & 63;
    const int w    = threadIdx.x >> 6;
    const int wr = w >> 1, wc = w & 1;
    const int q15 = lane & 15, g = lane >> 4;
    const int bm = blockIdx.x * 128, bn = blockIdx.y * 128;
    const int r0 = bm + wr * 64 + q15;
    const int c0 = bn + wc * 64 + q15;

    v4f acc[4][4];
#pragma unroll
    for (int i = 0; i < 4; ++i)
#pragma unroll
        for (int j = 0; j < 4; ++j)
#pragma unroll
            for (int r = 0; r < 4; ++r) acc[i][j][r] = 0.f;

    const int nk = K >> 5;
    for (int ks = 0; ks < nk; ++ks) {
        const int k0 = ks * 32 + g * 8;
        v8s afr[4], bfr[4];
#pragma unroll
        for (int mi = 0; mi < 4; ++mi) {
            const int row = r0 + mi * 16;
            if constexpr (ASRC == 0) {
                afr[mi] = *reinterpret_cast<const v8s*>(Abf + (size_t)row * K + k0);
            } else if constexpr (ASRC == 1) {
                const float* ap = Af + (size_t)row * CD + k0;
                v4f a = *reinterpret_cast<const v4f*>(ap);
                v4f b = *reinterpret_cast<const v4f*>(ap + 4);
                v8s t;
#pragma unroll
                for (int j = 0; j < 4; ++j) { t[j] = (short)f2bf(a[j]); t[j + 4] = (short)f2bf(b[j]); }
                afr[mi] = t;
            } else {
                if (k0 < 256) {
                    const float* ap = Af + (size_t)row * CD + k0;
                    v4f a = *reinterpret_cast<const v4f*>(ap);
                    v4f b = *reinterpret_cast<const v4f*>(ap + 4);
                    v8s t;
#pragma unroll
                    for (int j = 0; j < 4; ++j) { t[j] = (short)f2bf(a[j]); t[j + 4] = (short)f2bf(b[j]); }
                    afr[mi] = t;
                } else {
                    afr[mi] = *reinterpret_cast<const v8s*>(A2 + (size_t)row * CD + (k0 - 256));
                }
            }
        }
#pragma unroll
        for (int ni = 0; ni < 4; ++ni)
            bfr[ni] = *reinterpret_cast<const v8s*>(WT + (size_t)(c0 + ni * 16) * K + k0);
#pragma unroll
        for (int mi = 0; mi < 4; ++mi)
#pragma unroll
            for (int ni = 0; ni < 4; ++ni)
                acc[mi][ni] = __builtin_amdgcn_mfma_f32_16x16x32_bf16(afr[mi], bfr[ni], acc[mi][ni], 0, 0, 0);
    }

#pragma unroll
    for (int ni = 0; ni < 4; ++ni) {
        const int col = c0 + ni * 16;
        const float sc  = gamma[col] * rsqrtf(bvar[col] + 1e-3f);
        const float tc  = beta[col] - bmean[col] * sc;
        const float bia = BIAS ? bias[col] : 0.f;
#pragma unroll
        for (int mi = 0; mi < 4; ++mi) {
            if constexpr (OUT == 2) {
                const int row0 = bm + wr * 64 + mi * 16 + g * 4;
                v4u pk;
#pragma unroll
                for (int r = 0; r < 4; ++r) {
                    float z = acc[mi][ni][r] + bia;
                    z = z * sc + tc;
                    if (RELU) z = fmaxf(z, 0.f);
                    pk[r] = f2bf(z);
                }
                const int bb = row0 >> 12, key = row0 & 4095;
                *reinterpret_cast<v4u*>(outb + ((size_t)(bb * CD + col)) * NPB + key) = pk;
            } else {
#pragma unroll
                for (int r = 0; r < 4; ++r) {
                    const int row = bm + wr * 64 + mi * 16 + g * 4 + r;
                    float z = acc[mi][ni][r] + bia;
                    z = z * sc + tc;
                    if (RELU) z = fmaxf(z, 0.f);
                    if (RES)  z += resid[(size_t)row * CD + col];
                    if constexpr (OUT == 1) outf[(size_t)row * CD + col] = z;
                    else                    outb[(size_t)row * CD + col] = f2bf(z);
                }
            }
        }
    }
}

// ---- async stage: K chunk [32][256] + V^T chunk [256][32] into LDS ----------
// global_load_lds writes linearly; XOR swizzles applied to the GLOBAL source
// address (rule #21). K: row swizzle ^((key&7)<<3) on 256-elem rows.
// V^T: c-pairs packed into 64-elem rows, swizzle ^(((c>>1)&7)<<3).
__device__ __forceinline__ void stage_kv(const ubf* __restrict__ kg, const ubf* __restrict__ vg,
                                         ubf* kd, ubf* vd, int wave, int lane) {
#pragma unroll
    for (int it = 0; it < 8; ++it) {
        const int Lb = it * 1024 + wave * 512;   // wave-uniform element base
        const int L  = Lb + lane * 8;            // this lane's element slot
        {   // K
            const int key = L >> 8, c8 = (L & 255) ^ ((key & 7) << 3);
            const ubf* src = kg + key * CD + c8;
            __builtin_amdgcn_global_load_lds(
                (const __attribute__((address_space(1))) unsigned*)src,
                (__attribute__((address_space(3))) unsigned*)(kd + Lb), 16, 0, 0);
        }
        {   // V^T packed: elem = (c>>1)*64 + (((c&1)<<5 | k) ^ (((c>>1)&7)<<3))
            const int cpair = L >> 6;
            const int rem   = (L & 63) ^ ((cpair & 7) << 3);
            const int c = cpair * 2 + (rem >> 5), k = rem & 31;
            const ubf* src = vg + (size_t)c * NPB + k;
            __builtin_amdgcn_global_load_lds(
                (const __attribute__((address_space(1))) unsigned*)src,
                (__attribute__((address_space(3))) unsigned*)(vd + Lb), 16, 0, 0);
        }
    }
}

// ---------------- flash attention: softmax(Q K^T / 16) V ---------------------
// 512 blocks x 128 threads (2 waves x 16 q-rows, QBLK=32, KVBLK=32).
// LDS 68KB -> 2 independent blocks/CU: one block's MFMA/VALU overlaps the
// other's LDS/barrier stalls. Double-buffered async staging as round 5.
__global__ __launch_bounds__(128) void k_attn(const ubf* __restrict__ qb, const ubf* __restrict__ kb,
                                              const ubf* __restrict__ vt, ubf* __restrict__ ao) {
    __shared__ __attribute__((aligned(16))) ubf kbuf[2][32 * 256];  // 2 x 16KB
    __shared__ __attribute__((aligned(16))) ubf vbuf[2][256 * 32];  // 2 x 16KB packed V^T
    __shared__ __attribute__((aligned(16))) ubf pls[2 * 16 * 64];   // 4KB per-wave P

    const int raw = blockIdx.x;                  // XCD swizzle: batch -> XCD pair
    const int xcd = raw & 7, slot = raw >> 3;    // slot 0..63
    const int b   = xcd >> 1;
    const int qt  = ((xcd & 1) << 6) | slot;     // 0..127 q-tiles of 32 per batch

    const int wave = threadIdx.x >> 6, lane = threadIdx.x & 63;
    const int q15 = lane & 15, g = lane >> 4;

    // Q fragments (B-operand of K @ Q^T)
    const ubf* qrow = qb + ((size_t)(b * NPB + qt * 32 + wave * 16 + q15)) * CD + g * 8;
    v8s qf[8];
#pragma unroll
    for (int cs = 0; cs < 8; ++cs) qf[cs] = *reinterpret_cast<const v8s*>(qrow + cs * 32);

    v4f oacc[16];
#pragma unroll
    for (int i = 0; i < 16; ++i)
#pragma unroll
        for (int r = 0; r < 4; ++r) oacc[i][r] = 0.f;
    float m_run = -3.0e38f, l_run = 0.f;

    const ubf* kgb = kb + (size_t)(b * NPB) * CD;
    const ubf* vgb = vt + (size_t)b * CD * NPB;
    ubf* pw = pls + wave * 1024;
    const int swzP = (q15 & 7) << 3;

    // prologue: stage chunk 0 into buffer 0
    stage_kv(kgb, vgb, kbuf[0], vbuf[0], wave, lane);
    __syncthreads();

    for (int kc = 0; kc < 128; ++kc) {
        const int cur = kc & 1;
        const ubf* kls = kbuf[cur];
        const ubf* vls = vbuf[cur];

        // issue next chunk's loads BEFORE compute — latency hides under MFMA
        if (kc + 1 < 128)
            stage_kv(kgb + (size_t)(kc + 1) * 32 * CD, vgb + (kc + 1) * 32,
                     kbuf[cur ^ 1], vbuf[cur ^ 1], wave, lane);

        // S' = K_chunk @ Q^T  (rows = 32 keys, cols = 16 q)
        v4f sacc[2];
#pragma unroll
        for (int f = 0; f < 2; ++f)
#pragma unroll
            for (int r = 0; r < 4; ++r) sacc[f][r] = 0.f;
#pragma unroll
        for (int cs = 0; cs < 8; ++cs)
#pragma unroll
            for (int f = 0; f < 2; ++f) {
                const int key = 16 * f + q15;
                v8s af = *reinterpret_cast<const v8s*>(&kls[(key * CD + cs * 32 + g * 8) ^ ((key & 7) << 3)]);
                sacc[f] = __builtin_amdgcn_mfma_f32_16x16x32_bf16(af, qf[cs], sacc[f], 0, 0, 0);
            }

        // online softmax with defer-rescale (THR=8)
        float mloc = -3.0e38f;
#pragma unroll
        for (int f = 0; f < 2; ++f)
#pragma unroll
            for (int r = 0; r < 4; ++r) {
                float x = sacc[f][r] * 0.0625f;
                sacc[f][r] = x;
                mloc = fmaxf(mloc, x);
            }
        mloc = fmaxf(mloc, __shfl_xor(mloc, 16));
        mloc = fmaxf(mloc, __shfl_xor(mloc, 32));
        if (!__all(mloc <= m_run + 8.0f)) {
            const float mnew  = fmaxf(m_run, mloc);
            const float alpha = __expf(m_run - mnew);
            l_run *= alpha;
#pragma unroll
            for (int i = 0; i < 16; ++i)
#pragma unroll
                for (int r = 0; r < 4; ++r) oacc[i][r] *= alpha;
            m_run = mnew;
        }
        float lloc = 0.f;
#pragma unroll
        for (int f = 0; f < 2; ++f)
#pragma unroll
            for (int r = 0; r < 4; ++r) {
                float p = __expf(sacc[f][r] - m_run);
                sacc[f][r] = p;
                lloc += p;
            }
        lloc += __shfl_xor(lloc, 16);
        lloc += __shfl_xor(lloc, 32);
        l_run += lloc;

        // P -> LDS (bf16 trunc), per-wave private region, row = 64 elem padded
#pragma unroll
        for (int f = 0; f < 2; ++f) {
            unsigned u0, u1, u2, u3;
            { union { float f; unsigned u; } c; c.f = sacc[f][0]; u0 = c.u; }
            { union { float f; unsigned u; } c; c.f = sacc[f][1]; u1 = c.u; }
            { union { float f; unsigned u; } c; c.f = sacc[f][2]; u2 = c.u; }
            { union { float f; unsigned u; } c; c.f = sacc[f][3]; u3 = c.u; }
            unsigned p01 = (u0 >> 16) | (u1 & 0xFFFF0000u);
            unsigned p23 = (u2 >> 16) | (u3 & 0xFFFF0000u);
            const int e = q15 * 64 + 16 * f + 4 * g;
            *reinterpret_cast<unsigned*>(&pw[(e)     ^ swzP]) = p01;
            *reinterpret_cast<unsigned*>(&pw[(e + 2) ^ swzP]) = p23;
        }
        // O^T += V^T_chunk @ P   (B-frag = P^T row q15, k = 8g..8g+8)
        v8s pb = *reinterpret_cast<const v8s*>(&pw[(q15 * 64 + 8 * g) ^ swzP]);
#pragma unroll
        for (int mt = 0; mt < 16; ++mt) {
            const int cp = 8 * mt + (q15 >> 1);      // (16mt+q15)>>1
            const int e  = cp * 64 + ((((q15 & 1) << 5) | (g << 3)) ^ ((q15 >> 1) << 3));
            v8s av = *reinterpret_cast<const v8s*>(&vls[e]);
            oacc[mt] = __builtin_amdgcn_mfma_f32_16x16x32_bf16(av, pb, oacc[mt], 0, 0, 0);
        }

        __syncthreads();   // drains prefetch (vmcnt 0) + syncs dbuf across waves
    }

    const float inv_l = 1.0f / l_run;
    ubf* aor = ao + ((size_t)(b * NPB + qt * 32 + wave * 16 + q15)) * CD;
#pragma unroll
    for (int mt = 0; mt < 16; ++mt) {
        v4u pk;
#pragma unroll
        for (int r = 0; r < 4; ++r) pk[r] = f2bf(oacc[mt][r] * inv_l);
        *reinterpret_cast<v4u*>(aor + 16 * mt + 4 * g) = pk;
    }
}

// ---------------- launcher ---------------------------------------------------
extern "C" void kernel_launch(void* const* d_in, const int* in_sizes, int n_in,
                              void* d_out, int out_size, void* d_ws, size_t ws_size,
                              hipStream_t stream) {
    const float* f_low   = (const float*)d_in[0];
    const float* f_high  = (const float*)d_in[1];
    const float* bott_W  = (const float*)d_in[2];
    const float* bott_b  = (const float*)d_in[3];
    const float* bott_g  = (const float*)d_in[4];
    const float* bott_be = (const float*)d_in[5];
    const float* bott_m  = (const float*)d_in[6];
    const float* bott_v  = (const float*)d_in[7];
    const float* qkv_W   = (const float*)d_in[8];
    const float* qkv_g   = (const float*)d_in[9];
    const float* qkv_be  = (const float*)d_in[10];
    const float* qkv_m   = (const float*)d_in[11];
    const float* qkv_v   = (const float*)d_in[12];
    const float* mlp_W   = (const float*)d_in[13];
    const float* mlp_g   = (const float*)d_in[14];
    const float* mlp_be  = (const float*)d_in[15];
    const float* mlp_m   = (const float*)d_in[16];
    const float* mlp_v   = (const float*)d_in[17];
    const float* fus_W   = (const float*)d_in[18];
    const float* fus_b   = (const float*)d_in[19];
    const float* fus_g   = (const float*)d_in[20];
    const float* fus_be  = (const float*)d_in[21];
    const float* fus_m   = (const float*)d_in[22];
    const float* fus_v   = (const float*)d_in[23];
    (void)in_sizes; (void)n_in; (void)out_size; (void)ws_size;

    char* ws = (char*)d_ws;
    const size_t MB = 1024 * 1024;
    float* xA = (float*)(ws);                       // 16.8 MB residual stream (in-place)
    ubf*   y  = (ubf*)  (ws + 17 * MB);             // 8.4 MB (also ao)
    ubf*   qB = (ubf*)  (ws + 26 * MB);             // 8.4 MB (also h1)
    ubf*   kB = (ubf*)  (ws + 35 * MB);             // 8.4 MB (also h2)
    ubf*   vT = (ubf*)  (ws + 44 * MB);             // 8.4 MB V^T [B][C][n]
    ubf*   wT = (ubf*)  (ws + 53 * MB);             // 1.7 MB, 12 transposed weights

    k_wtrans<<<dim3(8, 16, 12), dim3(32, 8), 0, stream>>>(bott_W, qkv_W, mlp_W, fus_W, wT);
    k_point_attn<<<dim3(4096), dim3(256), 0, stream>>>(f_low, xA);

    const dim3 gg(128, 2), tb(256);
    for (int i = 0; i < 3; ++i) {
        k_gemm<1, true, true, false, 0><<<gg, tb, 0, stream>>>(
            nullptr, xA, nullptr, wT + (size_t)(2 * i) * 65536, 256,
            bott_b + 2 * i * 256, bott_g + 2 * i * 256, bott_be + 2 * i * 256,
            bott_m + 2 * i * 256, bott_v + 2 * i * 256, nullptr, nullptr, y);
        k_gemm<0, true, true, true, 1><<<gg, tb, 0, stream>>>(
            y, nullptr, nullptr, wT + (size_t)(2 * i + 1) * 65536, 256,
            bott_b + (2 * i + 1) * 256, bott_g + (2 * i + 1) * 256, bott_be + (2 * i + 1) * 256,
            bott_m + (2 * i + 1) * 256, bott_v + (2 * i + 1) * 256, xA, xA, nullptr);
    }

    k_gemm<1, false, false, false, 0><<<gg, tb, 0, stream>>>(
        nullptr, xA, nullptr, wT + (size_t)6 * 65536, 256,
        nullptr, qkv_g + 0, qkv_be + 0, qkv_m + 0, qkv_v + 0, nullptr, nullptr, qB);
    k_gemm<1, false, false, false, 0><<<gg, tb, 0, stream>>>(
        nullptr, f_high, nullptr, wT + (size_t)7 * 65536, 256,
        nullptr, qkv_g + 256, qkv_be + 256, qkv_m + 256, qkv_v + 256, nullptr, nullptr, kB);
    k_gemm<1, false, false, false, 2><<<gg, tb, 0, stream>>>(
        nullptr, f_high, nullptr, wT + (size_t)8 * 65536, 256,
        nullptr, qkv_g + 512, qkv_be + 512, qkv_m + 512, qkv_v + 512, nullptr, nullptr, vT);

    k_attn<<<dim3(512), dim3(128), 0, stream>>>(qB, kB, vT, y);

    k_gemm<0, false, true, false, 0><<<gg, tb, 0, stream>>>(
        y, nullptr, nullptr, wT + (size_t)9 * 65536, 256,
        nullptr, mlp_g + 0, mlp_be + 0, mlp_m + 0, mlp_v + 0, nullptr, nullptr, qB);
    k_gemm<0, false, true, false, 0><<<gg, tb, 0, stream>>>(
        qB, nullptr, nullptr, wT + (size_t)10 * 65536, 256,
        nullptr, mlp_g + 256, mlp_be + 256, mlp_m + 256, mlp_v + 256, nullptr, nullptr, kB);

    k_gemm<2, true, true, false, 1><<<gg, tb, 0, stream>>>(
        nullptr, xA, kB, wT + (size_t)11 * 65536, 512,
        fus_b, fus_g, fus_be, fus_m, fus_v, nullptr, (float*)d_out, nullptr);
}

// Round 7
// 348.732 us; speedup vs baseline: 1.1361x; 1.1361x over previous
//
#include <hip/hip_runtime.h>
#include <cstdint>
#include <cstddef>

typedef float v4f __attribute__((ext_vector_type(4)));
typedef float v2f __attribute__((ext_vector_type(2)));
typedef short v8s __attribute__((ext_vector_type(8)));
typedef unsigned short v4u __attribute__((ext_vector_type(4)));

typedef unsigned short ubf;   // raw bf16 bits

#define NPTS 16384
#define CD   256
#define NBAT 4
#define NPB  4096

__device__ __forceinline__ float bf2f(ubf u) {
    union { unsigned u; float f; } c; c.u = ((unsigned)u) << 16; return c.f;
}
__device__ __forceinline__ ubf f2bf(float f) {
    union { float f; unsigned u; } c; c.f = f;
    unsigned u = c.u;
    u += 0x7fffu + ((u >> 16) & 1u);           // round-nearest-even
    return (ubf)(u >> 16);
}

// -------- weight transpose+convert: W[K][256] f32 -> WT[256][K] bf16 ---------
__global__ void k_wtrans(const float* __restrict__ bott, const float* __restrict__ qkv,
                         const float* __restrict__ mlp, const float* __restrict__ fus,
                         ubf* __restrict__ wt) {
    const int z = blockIdx.z;
    const float* src; int K; size_t doff;
    if (z < 6)       { src = bott + (size_t)z * 65536;       K = 256; doff = (size_t)z * 65536; }
    else if (z < 9)  { src = qkv  + (size_t)(z - 6) * 65536; K = 256; doff = (size_t)z * 65536; }
    else if (z < 11) { src = mlp  + (size_t)(z - 9) * 65536; K = 256; doff = (size_t)z * 65536; }
    else             { src = fus;                            K = 512; doff = (size_t)11 * 65536; }
    const int kt = blockIdx.y * 32, nt = blockIdx.x * 32;
    if (kt >= K) return;
    __shared__ ubf tile[32][33];
    const int tx = threadIdx.x, ty = threadIdx.y;   // block (32,8)
#pragma unroll
    for (int i = 0; i < 4; ++i)
        tile[ty * 4 + i][tx] = f2bf(src[(size_t)(kt + ty * 4 + i) * 256 + nt + tx]);
    __syncthreads();
    ubf* dst = wt + doff;
#pragma unroll
    for (int i = 0; i < 4; ++i)
        dst[(size_t)(nt + ty * 4 + i) * K + kt + tx] = tile[tx][ty * 4 + i];
}

// ---------------- point attention (reference's Point_Attentation) ------------
__global__ __launch_bounds__(256) void k_point_attn(const float* __restrict__ low,
                                                    float* __restrict__ xout) {
    const int lane = threadIdx.x & 63;
    const int row  = blockIdx.x * 4 + (threadIdx.x >> 6);
    const float* p = low + (size_t)row * CD + lane * 4;
    v4f v = *reinterpret_cast<const v4f*>(p);
    float d[4];
    float s = v[0] + v[1] + v[2] + v[3];
#pragma unroll
    for (int o = 32; o >= 1; o >>= 1) s += __shfl_xor(s, o);
    const float mean = s * (1.0f / 256.0f);
    float ss = 0.f;
#pragma unroll
    for (int i = 0; i < 4; ++i) { d[i] = v[i] - mean; ss += d[i] * d[i]; }
#pragma unroll
    for (int o = 32; o >= 1; o >>= 1) ss += __shfl_xor(ss, o);
    const float var = ss * (1.0f / 4095.0f);        // reference: /(n-1), n=4096
    const float dn  = 1.0f / (4.0f * (var + 1e-5f));
    v4f o;
#pragma unroll
    for (int i = 0; i < 4; ++i) {
        const float e   = d[i] * d[i] * dn + 0.5f;
        const float sig = 1.0f / (1.0f + __expf(-e));
        o[i] = v[i] * (1.0f + sig);
    }
    *reinterpret_cast<v4f*>(xout + (size_t)row * CD + lane * 4) = o;
}

// ---------------- fused GEMM + bias + BN + ReLU + residual -------------------
// C[M][256] = A[M][K] @ W[K][256], W given as WT[256][K] bf16.
// Block tile 128x128, 4 waves (2x2), wave tile 64x64. grid (M/128, N/128).
// ASRC: 0 = bf16 A (stride K), 1 = f32 A (stride 256), 2 = cat(f32 x | bf16 h)
// OUT:  0 = bf16 [row][col], 1 = f32 [row][col]
template<int ASRC, bool BIAS, bool RELU, bool RES, int OUT>
__global__ __launch_bounds__(256) void k_gemm(
    const ubf* __restrict__ Abf, const float* __restrict__ Af, const ubf* __restrict__ A2,
    const ubf* __restrict__ WT, const int K,
    const float* __restrict__ bias, const float* __restrict__ gamma, const float* __restrict__ beta,
    const float* __restrict__ bmean, const float* __restrict__ bvar,
    const float* __restrict__ resid, float* __restrict__ outf, ubf* __restrict__ outb) {
    const int lane = threadIdx.x & 63;
    const int w    = threadIdx.x >> 6;
    const int wr = w >> 1, wc = w & 1;
    const int q15 = lane & 15, g = lane >> 4;
    const int bm = blockIdx.x * 128, bn = blockIdx.y * 128;
    const int r0 = bm + wr * 64 + q15;
    const int c0 = bn + wc * 64 + q15;

    v4f acc[4][4];
#pragma unroll
    for (int i = 0; i < 4; ++i)
#pragma unroll
        for (int j = 0; j < 4; ++j)
#pragma unroll
            for (int r = 0; r < 4; ++r) acc[i][j][r] = 0.f;

    const int nk = K >> 5;
    for (int ks = 0; ks < nk; ++ks) {
        const int k0 = ks * 32 + g * 8;
        v8s afr[4], bfr[4];
#pragma unroll
        for (int mi = 0; mi < 4; ++mi) {
            const int row = r0 + mi * 16;
            if constexpr (ASRC == 0) {
                afr[mi] = *reinterpret_cast<const v8s*>(Abf + (size_t)row * K + k0);
            } else if constexpr (ASRC == 1) {
                const float* ap = Af + (size_t)row * CD + k0;
                v4f a = *reinterpret_cast<const v4f*>(ap);
                v4f b = *reinterpret_cast<const v4f*>(ap + 4);
                v8s t;
#pragma unroll
                for (int j = 0; j < 4; ++j) { t[j] = (short)f2bf(a[j]); t[j + 4] = (short)f2bf(b[j]); }
                afr[mi] = t;
            } else {
                if (k0 < 256) {
                    const float* ap = Af + (size_t)row * CD + k0;
                    v4f a = *reinterpret_cast<const v4f*>(ap);
                    v4f b = *reinterpret_cast<const v4f*>(ap + 4);
                    v8s t;
#pragma unroll
                    for (int j = 0; j < 4; ++j) { t[j] = (short)f2bf(a[j]); t[j + 4] = (short)f2bf(b[j]); }
                    afr[mi] = t;
                } else {
                    afr[mi] = *reinterpret_cast<const v8s*>(A2 + (size_t)row * CD + (k0 - 256));
                }
            }
        }
#pragma unroll
        for (int ni = 0; ni < 4; ++ni)
            bfr[ni] = *reinterpret_cast<const v8s*>(WT + (size_t)(c0 + ni * 16) * K + k0);
#pragma unroll
        for (int mi = 0; mi < 4; ++mi)
#pragma unroll
            for (int ni = 0; ni < 4; ++ni)
                acc[mi][ni] = __builtin_amdgcn_mfma_f32_16x16x32_bf16(afr[mi], bfr[ni], acc[mi][ni], 0, 0, 0);
    }

#pragma unroll
    for (int ni = 0; ni < 4; ++ni) {
        const int col = c0 + ni * 16;
        const float sc  = gamma[col] * rsqrtf(bvar[col] + 1e-3f);
        const float tc  = beta[col] - bmean[col] * sc;
        const float bia = BIAS ? bias[col] : 0.f;
#pragma unroll
        for (int mi = 0; mi < 4; ++mi) {
#pragma unroll
            for (int r = 0; r < 4; ++r) {
                const int row = bm + wr * 64 + mi * 16 + g * 4 + r;
                float z = acc[mi][ni][r] + bia;
                z = z * sc + tc;
                if (RELU) z = fmaxf(z, 0.f);
                if (RES)  z += resid[(size_t)row * CD + col];
                if constexpr (OUT == 1) outf[(size_t)row * CD + col] = z;
                else                    outb[(size_t)row * CD + col] = f2bf(z);
            }
        }
    }
}

// ---------------- fused QKV projection: one dispatch, 768 blocks -------------
// grid (128, 6): y>>1 = matrix (0=q from xA, 1=k from high, 2=v from high),
// y&1 = column half. v written transposed to vT[b][c][key].
__global__ __launch_bounds__(256) void k_qkv(
    const float* __restrict__ xA, const float* __restrict__ fh,
    const ubf* __restrict__ wTq,
    const float* __restrict__ qg, const float* __restrict__ qbe,
    const float* __restrict__ qm, const float* __restrict__ qv,
    ubf* __restrict__ qB, ubf* __restrict__ kB, ubf* __restrict__ vT) {
    const int m = blockIdx.y >> 1;               // 0=q, 1=k, 2=v
    const float* Af = (m == 0) ? xA : fh;
    const ubf* WT = wTq + m * 65536;
    const float* gamma = qg + m * 256;
    const float* beta  = qbe + m * 256;
    const float* bmean = qm + m * 256;
    const float* bvar  = qv + m * 256;

    const int lane = threadIdx.x & 63;
    const int w    = threadIdx.x >> 6;
    const int wr = w >> 1, wc = w & 1;
    const int q15 = lane & 15, g = lane >> 4;
    const int bm = blockIdx.x * 128, bn = (blockIdx.y & 1) * 128;
    const int r0 = bm + wr * 64 + q15;
    const int c0 = bn + wc * 64 + q15;

    v4f acc[4][4];
#pragma unroll
    for (int i = 0; i < 4; ++i)
#pragma unroll
        for (int j = 0; j < 4; ++j)
#pragma unroll
            for (int r = 0; r < 4; ++r) acc[i][j][r] = 0.f;

    for (int ks = 0; ks < 8; ++ks) {
        const int k0 = ks * 32 + g * 8;
        v8s afr[4], bfr[4];
#pragma unroll
        for (int mi = 0; mi < 4; ++mi) {
            const float* ap = Af + (size_t)(r0 + mi * 16) * CD + k0;
            v4f a = *reinterpret_cast<const v4f*>(ap);
            v4f b = *reinterpret_cast<const v4f*>(ap + 4);
            v8s t;
#pragma unroll
            for (int j = 0; j < 4; ++j) { t[j] = (short)f2bf(a[j]); t[j + 4] = (short)f2bf(b[j]); }
            afr[mi] = t;
        }
#pragma unroll
        for (int ni = 0; ni < 4; ++ni)
            bfr[ni] = *reinterpret_cast<const v8s*>(WT + (size_t)(c0 + ni * 16) * 256 + k0);
#pragma unroll
        for (int mi = 0; mi < 4; ++mi)
#pragma unroll
            for (int ni = 0; ni < 4; ++ni)
                acc[mi][ni] = __builtin_amdgcn_mfma_f32_16x16x32_bf16(afr[mi], bfr[ni], acc[mi][ni], 0, 0, 0);
    }

    ubf* outb = (m == 0) ? qB : kB;
#pragma unroll
    for (int ni = 0; ni < 4; ++ni) {
        const int col = c0 + ni * 16;
        const float sc = gamma[col] * rsqrtf(bvar[col] + 1e-3f);
        const float tc = beta[col] - bmean[col] * sc;
#pragma unroll
        for (int mi = 0; mi < 4; ++mi) {
            if (m == 2) {
                const int row0 = bm + wr * 64 + mi * 16 + g * 4;
                v4u pk;
#pragma unroll
                for (int r = 0; r < 4; ++r) pk[r] = f2bf(acc[mi][ni][r] * sc + tc);
                const int bb = row0 >> 12, key = row0 & 4095;
                *reinterpret_cast<v4u*>(vT + ((size_t)(bb * CD + col)) * NPB + key) = pk;
            } else {
#pragma unroll
                for (int r = 0; r < 4; ++r) {
                    const int row = bm + wr * 64 + mi * 16 + g * 4 + r;
                    outb[(size_t)row * CD + col] = f2bf(acc[mi][ni][r] * sc + tc);
                }
            }
        }
    }
}

// ---- async stage: K chunk [64][256] + V^T chunk [256][64] into LDS ----------
// global_load_lds writes linearly; XOR swizzle applied to the GLOBAL source
// address (rule #21: both-sides-or-neither).
__device__ __forceinline__ void stage_kv(const ubf* __restrict__ kg, const ubf* __restrict__ vg,
                                         ubf* kd, ubf* vd, int wave, int lane) {
#pragma unroll
    for (int it = 0; it < 8; ++it) {
        const int Lb = it * 2048 + wave * 512;   // wave-uniform element base
        const int L  = Lb + lane * 8;            // this lane's element slot
        {   // K: LDS[key*256 + c] holds K[key][c ^ ((key&7)<<3)]
            const int key = L >> 8, c8 = L & 255;
            const ubf* src = kg + key * CD + (c8 ^ ((key & 7) << 3));
            __builtin_amdgcn_global_load_lds(
                (const __attribute__((address_space(1))) unsigned*)src,
                (__attribute__((address_space(3))) unsigned*)(kd + Lb), 16, 0, 0);
        }
        {   // V^T: LDS[c*64 + k] holds V^T[c][k ^ ((c&7)<<3)]
            const int c = L >> 6, k8 = L & 63;
            const ubf* src = vg + (size_t)c * NPB + (k8 ^ ((c & 7) << 3));
            __builtin_amdgcn_global_load_lds(
                (const __attribute__((address_space(1))) unsigned*)src,
                (__attribute__((address_space(3))) unsigned*)(vd + Lb), 16, 0, 0);
        }
    }
}

// ---------------- flash attention, KV-split x2 across blocks -----------------
// 512 blocks x 256 threads. Block (b, half, qt): 64 q-rows (4 waves x 16),
// keys [half*2048, half*2048+2048) in 32 chunks of 64. Single-buffered LDS
// (72KB -> 2 blocks/CU, 8 waves/CU): co-resident block's compute hides this
// block's staging. Writes unnormalized bf16 partial O + (m,l); k_merge combines.
__global__ __launch_bounds__(256) void k_attn(const ubf* __restrict__ qb, const ubf* __restrict__ kb,
                                              const ubf* __restrict__ vt,
                                              ubf* __restrict__ o0, ubf* __restrict__ o1,
                                              float* __restrict__ ml) {
    __shared__ __attribute__((aligned(16))) ubf kls[64 * 256];   // 32KB
    __shared__ __attribute__((aligned(16))) ubf vls[256 * 64];   // 32KB (V^T)
    __shared__ __attribute__((aligned(16))) ubf pls[4 * 16 * 64]; // 8KB per-wave P

    const int raw = blockIdx.x;                  // XCD swizzle: xcd = (b<<1)|half
    const int xcd = raw & 7, qt = raw >> 3;
    const int b = xcd >> 1, half = xcd & 1;

    const int wave = threadIdx.x >> 6, lane = threadIdx.x & 63;
    const int q15 = lane & 15, g = lane >> 4;

    // Q fragments (B-operand of K @ Q^T)
    const ubf* qrow = qb + ((size_t)(b * NPB + qt * 64 + wave * 16 + q15)) * CD + g * 8;
    v8s qf[8];
#pragma unroll
    for (int cs = 0; cs < 8; ++cs) qf[cs] = *reinterpret_cast<const v8s*>(qrow + cs * 32);

    v4f oacc[16];
#pragma unroll
    for (int i = 0; i < 16; ++i)
#pragma unroll
        for (int r = 0; r < 4; ++r) oacc[i][r] = 0.f;
    float m_run = -3.0e38f, l_run = 0.f;

    const ubf* kgb = kb + ((size_t)(b * NPB) + half * 2048) * CD;
    const ubf* vgb = vt + (size_t)b * CD * NPB + half * 2048;
    ubf* pw = pls + wave * 1024;

    for (int kc = 0; kc < 32; ++kc) {
        stage_kv(kgb + (size_t)kc * 64 * CD, vgb + kc * 64, kls, vls, wave, lane);
        __syncthreads();                         // vmcnt(0) drain + barrier

        // S' = K_chunk @ Q^T  (rows = keys, cols = q)
        v4f sacc[4];
#pragma unroll
        for (int f = 0; f < 4; ++f)
#pragma unroll
            for (int r = 0; r < 4; ++r) sacc[f][r] = 0.f;
#pragma unroll
        for (int cs = 0; cs < 8; ++cs)
#pragma unroll
            for (int f = 0; f < 4; ++f) {
                const int key = 16 * f + q15;
                v8s af = *reinterpret_cast<const v8s*>(&kls[(key * CD + cs * 32 + g * 8) ^ ((key & 7) << 3)]);
                sacc[f] = __builtin_amdgcn_mfma_f32_16x16x32_bf16(af, qf[cs], sacc[f], 0, 0, 0);
            }

        // online softmax with defer-rescale (THR=8)
        float mloc = -3.0e38f;
#pragma unroll
        for (int f = 0; f < 4; ++f)
#pragma unroll
            for (int r = 0; r < 4; ++r) {
                float x = sacc[f][r] * 0.0625f;
                sacc[f][r] = x;
                mloc = fmaxf(mloc, x);
            }
        mloc = fmaxf(mloc, __shfl_xor(mloc, 16));
        mloc = fmaxf(mloc, __shfl_xor(mloc, 32));
        if (!__all(mloc <= m_run + 8.0f)) {
            const float mnew  = fmaxf(m_run, mloc);
            const float alpha = __expf(m_run - mnew);
            l_run *= alpha;
#pragma unroll
            for (int i = 0; i < 16; ++i)
#pragma unroll
                for (int r = 0; r < 4; ++r) oacc[i][r] *= alpha;
            m_run = mnew;
        }
        float lloc = 0.f;
#pragma unroll
        for (int f = 0; f < 4; ++f)
#pragma unroll
            for (int r = 0; r < 4; ++r) {
                float p = __expf(sacc[f][r] - m_run);
                sacc[f][r] = p;
                lloc += p;
            }
        lloc += __shfl_xor(lloc, 16);
        lloc += __shfl_xor(lloc, 32);
        l_run += lloc;

        // P -> LDS (bf16 trunc), per-wave private region
#pragma unroll
        for (int f = 0; f < 4; ++f) {
            unsigned u0, u1, u2, u3;
            { union { float f; unsigned u; } c; c.f = sacc[f][0]; u0 = c.u; }
            { union { float f; unsigned u; } c; c.f = sacc[f][1]; u1 = c.u; }
            { union { float f; unsigned u; } c; c.f = sacc[f][2]; u2 = c.u; }
            { union { float f; unsigned u; } c; c.f = sacc[f][3]; u3 = c.u; }
            unsigned p01 = (u0 >> 16) | (u1 & 0xFFFF0000u);
            unsigned p23 = (u2 >> 16) | (u3 & 0xFFFF0000u);
            const int e = q15 * 64 + 16 * f + 4 * g;
            *reinterpret_cast<unsigned*>(&pw[(e)     ^ ((q15 & 7) << 3)]) = p01;
            *reinterpret_cast<unsigned*>(&pw[(e + 2) ^ ((q15 & 7) << 3)]) = p23;
        }
        // O^T += V^T_chunk @ P
        v8s pb0 = *reinterpret_cast<const v8s*>(&pw[(q15 * 64 +  0 + 8 * g) ^ ((q15 & 7) << 3)]);
        v8s pb1 = *reinterpret_cast<const v8s*>(&pw[(q15 * 64 + 32 + 8 * g) ^ ((q15 & 7) << 3)]);
#pragma unroll
        for (int mt = 0; mt < 16; ++mt) {
            const int c = 16 * mt + q15;
            v8s av0 = *reinterpret_cast<const v8s*>(&vls[(c * 64 +  0 + 8 * g) ^ ((c & 7) << 3)]);
            oacc[mt] = __builtin_amdgcn_mfma_f32_16x16x32_bf16(av0, pb0, oacc[mt], 0, 0, 0);
            v8s av1 = *reinterpret_cast<const v8s*>(&vls[(c * 64 + 32 + 8 * g) ^ ((c & 7) << 3)]);
            oacc[mt] = __builtin_amdgcn_mfma_f32_16x16x32_bf16(av1, pb1, oacc[mt], 0, 0, 0);
        }

        __syncthreads();   // all waves done reading this buffer before restage
    }

    // epilogue: unnormalized partial O (bf16) + per-row (m, l)
    const int grow = b * NPB + qt * 64 + wave * 16 + q15;
    ubf* aor = (half ? o1 : o0) + (size_t)grow * CD;
#pragma unroll
    for (int mt = 0; mt < 16; ++mt) {
        v4u pk;
#pragma unroll
        for (int r = 0; r < 4; ++r) pk[r] = f2bf(oacc[mt][r]);
        *reinterpret_cast<v4u*>(aor + 16 * mt + 4 * g) = pk;
    }
    if (g == 0) {
        v2f d; d[0] = m_run; d[1] = l_run;
        *reinterpret_cast<v2f*>(ml + (size_t)(half * NPTS + grow) * 2) = d;
    }
}

// ---------------- merge the two KV-half partials -----------------------------
__global__ __launch_bounds__(256) void k_merge(ubf* __restrict__ o0, const ubf* __restrict__ o1,
                                               const float* __restrict__ ml) {
    const int row  = blockIdx.x * 4 + (threadIdx.x >> 6);
    const int lane = threadIdx.x & 63;
    v2f a = *reinterpret_cast<const v2f*>(ml + (size_t)row * 2);
    v2f c = *reinterpret_cast<const v2f*>(ml + (size_t)(NPTS + row) * 2);
    const float mx = fmaxf(a[0], c[0]);
    const float w0 = __expf(a[0] - mx), w1 = __expf(c[0] - mx);
    const float inv = 1.0f / (w0 * a[1] + w1 * c[1]);
    ubf* p0 = o0 + (size_t)row * CD + lane * 4;
    const ubf* p1 = o1 + (size_t)row * CD + lane * 4;
    v4u u0 = *reinterpret_cast<const v4u*>(p0);
    v4u u1 = *reinterpret_cast<const v4u*>(p1);
    v4u o;
#pragma unroll
    for (int r = 0; r < 4; ++r)
        o[r] = f2bf((w0 * bf2f(u0[r]) + w1 * bf2f(u1[r])) * inv);
    *reinterpret_cast<v4u*>(p0) = o;
}

// ---------------- launcher ---------------------------------------------------
extern "C" void kernel_launch(void* const* d_in, const int* in_sizes, int n_in,
                              void* d_out, int out_size, void* d_ws, size_t ws_size,
                              hipStream_t stream) {
    const float* f_low   = (const float*)d_in[0];
    const float* f_high  = (const float*)d_in[1];
    const float* bott_W  = (const float*)d_in[2];
    const float* bott_b  = (const float*)d_in[3];
    const float* bott_g  = (const float*)d_in[4];
    const float* bott_be = (const float*)d_in[5];
    const float* bott_m  = (const float*)d_in[6];
    const float* bott_v  = (const float*)d_in[7];
    const float* qkv_W   = (const float*)d_in[8];
    const float* qkv_g   = (const float*)d_in[9];
    const float* qkv_be  = (const float*)d_in[10];
    const float* qkv_m   = (const float*)d_in[11];
    const float* qkv_v   = (const float*)d_in[12];
    const float* mlp_W   = (const float*)d_in[13];
    const float* mlp_g   = (const float*)d_in[14];
    const float* mlp_be  = (const float*)d_in[15];
    const float* mlp_m   = (const float*)d_in[16];
    const float* mlp_v   = (const float*)d_in[17];
    const float* fus_W   = (const float*)d_in[18];
    const float* fus_b   = (const float*)d_in[19];
    const float* fus_g   = (const float*)d_in[20];
    const float* fus_be  = (const float*)d_in[21];
    const float* fus_m   = (const float*)d_in[22];
    const float* fus_v   = (const float*)d_in[23];
    (void)in_sizes; (void)n_in; (void)out_size; (void)ws_size;

    char* ws = (char*)d_ws;
    const size_t MB = 1024 * 1024;
    float* xA = (float*)(ws);                       // 16.8 MB residual stream (in-place)
    ubf*   y  = (ubf*)  (ws + 17 * MB);             // 8.4 MB (attn half0 partial -> final ao)
    ubf*   qB = (ubf*)  (ws + 26 * MB);             // 8.4 MB (Q, later h1)
    ubf*   kB = (ubf*)  (ws + 35 * MB);             // 8.4 MB (K, later h2)
    ubf*   vT = (ubf*)  (ws + 44 * MB);             // 8.4 MB V^T [B][C][n]
    ubf*   wT = (ubf*)  (ws + 53 * MB);             // 1.7 MB, 12 transposed weights
    ubf*   o1 = (ubf*)  (ws + 56 * MB);             // 8.4 MB attn half1 partial
    float* ml = (float*)(ws + 65 * MB);             // 512 KB (m,l) pairs x 2 halves

    k_wtrans<<<dim3(8, 16, 12), dim3(32, 8), 0, stream>>>(bott_W, qkv_W, mlp_W, fus_W, wT);
    k_point_attn<<<dim3(4096), dim3(256), 0, stream>>>(f_low, xA);

    const dim3 gg(128, 2), tb(256);
    for (int i = 0; i < 3; ++i) {
        k_gemm<1, true, true, false, 0><<<gg, tb, 0, stream>>>(
            nullptr, xA, nullptr, wT + (size_t)(2 * i) * 65536, 256,
            bott_b + 2 * i * 256, bott_g + 2 * i * 256, bott_be + 2 * i * 256,
            bott_m + 2 * i * 256, bott_v + 2 * i * 256, nullptr, nullptr, y);
        k_gemm<0, true, true, true, 1><<<gg, tb, 0, stream>>>(
            y, nullptr, nullptr, wT + (size_t)(2 * i + 1) * 65536, 256,
            bott_b + (2 * i + 1) * 256, bott_g + (2 * i + 1) * 256, bott_be + (2 * i + 1) * 256,
            bott_m + (2 * i + 1) * 256, bott_v + (2 * i + 1) * 256, xA, xA, nullptr);
    }

    k_qkv<<<dim3(128, 6), tb, 0, stream>>>(xA, f_high, wT + (size_t)6 * 65536,
                                           qkv_g, qkv_be, qkv_m, qkv_v, qB, kB, vT);

    k_attn<<<dim3(512), tb, 0, stream>>>(qB, kB, vT, y, o1, ml);
    k_merge<<<dim3(4096), tb, 0, stream>>>(y, o1, ml);

    k_gemm<0, false, true, false, 0><<<gg, tb, 0, stream>>>(
        y, nullptr, nullptr, wT + (size_t)9 * 65536, 256,
        nullptr, mlp_g + 0, mlp_be + 0, mlp_m + 0, mlp_v + 0, nullptr, nullptr, qB);
    k_gemm<0, false, true, false, 0><<<gg, tb, 0, stream>>>(
        qB, nullptr, nullptr, wT + (size_t)10 * 65536, 256,
        nullptr, mlp_g + 256, mlp_be + 256, mlp_m + 256, mlp_v + 256, nullptr, nullptr, kB);

    k_gemm<2, true, true, false, 1><<<gg, tb, 0, stream>>>(
        nullptr, xA, kB, wT + (size_t)11 * 65536, 512,
        fus_b, fus_g, fus_be, fus_m, fus_v, nullptr, (float*)d_out, nullptr);
}